// Round 2
// baseline (535.233 us; speedup 1.0000x reference)
//
#include <hip/hip_runtime.h>
#include <hip/hip_bf16.h>

// ---------------------------------------------------------------------------
// swin_transformer_angular_tan: qkv GEMM -> attention -> proj GEMM.
// Round 5: UNFUSE proj from the attention kernel.
//   Post-mortem R4: head-level software pipeline regressed (171us vs 148.8):
//   >63 outstanding vmem per wave -> inexpressible vmcnt -> conservative
//   drains. Attention is latency-bound at 22% occupancy, pinned by the 64KB
//   aout LDS that only exists to feed the fused proj.
//   Fix: attention kernel keeps only 16KB pbuf -> 4 blocks/CU (2x waves);
//   proj becomes a standalone gemm_bt<0> (proven structure) reading a 64MB
//   bf16 obuf (reuses the xb workspace region, stream-ordered safe).
//   Kept from R4 (correctness-verified): exp2 softmax w/ log2e-prescaled
//   bias, batched b64 P^T staging, packed b64 output writes.
//   Reverted from R4: 3-deep load pipeline, phase-2 ping-pong.
// ---------------------------------------------------------------------------

typedef __bf16 bf16_t;
typedef bf16_t bf16x4 __attribute__((ext_vector_type(4)));
typedef bf16_t bf16x8 __attribute__((ext_vector_type(8)));
typedef float  f32x4  __attribute__((ext_vector_type(4)));

#define NWIN   1024
#define NTOK   64
#define DIM    512
#define NHEADS 16
#define HD     32
#define MTOT   (NWIN*NTOK)      // 65536
#define QKVN   (3*DIM)          // 1536
#define SCLG2E 0.25503494f      // (1/sqrt(32)) * log2(e); bias pre-scaled by log2(e)

// ---------------- async global->LDS (16B per lane, wave-uniform LDS base) ---
__device__ __forceinline__ void async_copy16(const void* g, void* lds_generic) {
    __builtin_amdgcn_global_load_lds(
        (__attribute__((address_space(1))) unsigned int*)(unsigned long long)g,
        (__attribute__((address_space(3))) unsigned int*)(unsigned int)(unsigned long long)lds_generic,
        16, 0, 0);
}

// ---------------- fp32 -> bf16 convert (8 elems/thread) ---------------------
__global__ void cvt_f32_bf16(const float* __restrict__ in, bf16_t* __restrict__ out, int n8) {
    int i = blockIdx.x * blockDim.x + threadIdx.x;
    if (i >= n8) return;
    const float4* p = (const float4*)in;
    float4 a = p[2*i], b = p[2*i+1];
    bf16x8 o;
    o[0]=(bf16_t)a.x; o[1]=(bf16_t)a.y; o[2]=(bf16_t)a.z; o[3]=(bf16_t)a.w;
    o[4]=(bf16_t)b.x; o[5]=(bf16_t)b.y; o[6]=(bf16_t)b.z; o[7]=(bf16_t)b.w;
    ((bf16x8*)out)[i] = o;
}

// ---------------- bias table: bias[h][i][j] * log2e, 16 x 64 x 64 -----------
__global__ void bias_kernel(const float* __restrict__ ap, const float* __restrict__ bp,
                            const float* __restrict__ ar, const float* __restrict__ br,
                            const float* __restrict__ theta_max, float* __restrict__ bias) {
    int idx = blockIdx.x * 256 + threadIdx.x;   // 0..65535
    int h  = idx >> 12;
    int ij = idx & 4095;
    int i = ij >> 6, j = ij & 63;
    int ri = i >> 3, ci = i & 7, rj = j >> 3, cj = j & 7;
    int rad = ri - rj, az = ci - cj;              // -7..7
    int idx_r  = rad < 0 ? rad + 15 : rad;        // python % 15
    int idx_az = az  < 0 ? az  + 15 : az;
    float azang = (float)az * 0.19634954084936207f;       // 2*pi/32
    float rang  = (float)rad * (theta_max[0] * (1.0f/32.0f));
    float v = ap[idx_az*NHEADS + h] * cosf(azang) + bp[idx_az*NHEADS + h] * sinf(azang)
            + ar[idx_r *NHEADS + h] * cosf(rang)  + br[idx_r *NHEADS + h] * sinf(rang);
    bias[idx] = v * 1.4426950408889634f;   // pre-scale by log2(e) for exp2 softmax
}

// ---------------- BT-GEMM: C[M,N] = A[M,K] * Bt[N,K]^T + bias[N] ------------
// 128x128 tile, BK=64, 4 waves each 64x64 (4x4 MFMA 16x16x32).
// LDS tiles XOR-swizzled: row r, 16B-chunk cb stored at position cb^(r&7).
template<int OUT_BF16>
__global__ __launch_bounds__(256, 2)
void gemm_bt(const bf16_t* __restrict__ A, const bf16_t* __restrict__ Bt,
             const float* __restrict__ bias, void* __restrict__ C,
             int M, int N, int K, int ntiles) {
    __shared__ bf16_t sA[128*64];
    __shared__ bf16_t sB[128*64];

    int bid = blockIdx.x;
    int bm = bid / ntiles, bn = bid % ntiles;
    int tid = threadIdx.x;
    int w = tid >> 6, lane = tid & 63;
    int quad = lane >> 4, l16 = lane & 15;
    int wm = w >> 1, wn = w & 1;               // 2x2 wave grid

    f32x4 acc[4][4] = {};

    const bf16_t* Abase = A  + (size_t)(bm*128) * K;
    const bf16_t* Bbase = Bt + (size_t)(bn*128) * K;

    for (int k0 = 0; k0 < K; k0 += 64) {
        for (int i = 0; i < 4; ++i) {
            int off = w*4096 + i*1024 + lane*16;  // byte offset in tile
            int r  = off >> 7;                    // row (128B rows)
            int pb = (off >> 4) & 7;              // physical 16B chunk
            int cb = pb ^ (r & 7);                // logical chunk (swizzle)
            async_copy16(Abase + (size_t)r*K + k0 + cb*8, (char*)sA + w*4096 + i*1024);
            async_copy16(Bbase + (size_t)r*K + k0 + cb*8, (char*)sB + w*4096 + i*1024);
        }
        __syncthreads();

        for (int kk = 0; kk < 64; kk += 32) {
            bf16x8 af[4], bf[4];
            for (int mi = 0; mi < 4; ++mi) {
                int r  = wm*64 + mi*16 + l16;
                int cb = (kk >> 3) + quad;
                int pb = cb ^ (r & 7);
                af[mi] = *(const bf16x8*)((const char*)sA + r*128 + pb*16);
            }
            for (int ni = 0; ni < 4; ++ni) {
                int r  = wn*64 + ni*16 + l16;
                int cb = (kk >> 3) + quad;
                int pb = cb ^ (r & 7);
                bf[ni] = *(const bf16x8*)((const char*)sB + r*128 + pb*16);
            }
            for (int mi = 0; mi < 4; ++mi)
                for (int ni = 0; ni < 4; ++ni)
                    acc[mi][ni] = __builtin_amdgcn_mfma_f32_16x16x32_bf16(
                        af[mi], bf[ni], acc[mi][ni], 0, 0, 0);
        }
        __syncthreads();
    }

    for (int ni = 0; ni < 4; ++ni) {
        int col = bn*128 + wn*64 + ni*16 + l16;
        float bv = bias[col];
        for (int mi = 0; mi < 4; ++mi) {
            int row0 = bm*128 + wm*64 + mi*16 + quad*4;
            f32x4 a = acc[mi][ni];
            for (int reg = 0; reg < 4; ++reg) {
                float v = a[reg] + bv;
                size_t o = (size_t)(row0 + reg) * N + col;
                if (OUT_BF16) ((bf16_t*)C)[o] = (bf16_t)v;
                else          ((float*)C)[o]  = v;
            }
        }
    }
}

// ---------------- attention only: one block per window, 4 heads/wave --------
// No __syncthreads, LDS = 16KB pbuf only -> 4 blocks/CU (VGPR-capped).
__global__ __launch_bounds__(256, 4)
void attn_kernel(const bf16_t* __restrict__ qkv, const float* __restrict__ bias,
                 bf16_t* __restrict__ obuf) {
    __shared__ bf16_t pbuf[4][2048];  // per-wave P^T staging, 4KB each

    int b = blockIdx.x;
    int tid = threadIdx.x;
    int w = tid >> 6, lane = tid & 63, quad = lane >> 4, l16 = lane & 15;
    int qh = quad >> 1, ql = quad & 1;
    const bf16_t* base = qkv + (size_t)(b*64) * QKVN;
    f32x4 zero = {0.f, 0.f, 0.f, 0.f};
    bf16_t* pb = pbuf[w];

    #pragma unroll 1
    for (int t = 0; t < 4; ++t) {
        int h = w*4 + t;

        // K rows -> S^T A-frags; Q rows -> S^T B-frags (coalesced b128)
        bf16x8 ak[4], bq[4];
        #pragma unroll
        for (int jt = 0; jt < 4; ++jt)
            ak[jt] = *(const bf16x8*)(base + (size_t)(jt*16 + l16)*QKVN + 512 + h*32 + quad*8);
        #pragma unroll
        for (int it = 0; it < 4; ++it)
            bq[it] = *(const bf16x8*)(base + (size_t)(it*16 + l16)*QKVN + h*32 + quad*8);

        // V^T A-frags via strided scalar loads: elem e -> v[ks*32+quad*8+e][h*32+dt*16+l16]
        bf16x8 av[2][2];
        #pragma unroll
        for (int dt = 0; dt < 2; ++dt)
            #pragma unroll
            for (int ks = 0; ks < 2; ++ks) {
                const bf16_t* vb = base + (size_t)(ks*32 + quad*8)*QKVN + 1024 + h*32 + dt*16 + l16;
                bf16x8 tmp;
                #pragma unroll
                for (int e = 0; e < 8; ++e) tmp[e] = vb[(size_t)e*QKVN];
                av[dt][ks] = tmp;
            }

        const float* bh = bias + h*4096;
        f32x4 accO[2][4];
        float s[4];
        #pragma unroll
        for (int it = 0; it < 4; ++it) { s[it] = 0.f; accO[0][it] = zero; accO[1][it] = zero; }

        #pragma unroll
        for (int ks = 0; ks < 2; ++ks) {
            // bias for rows j = ks*32 .. ks*32+31 (L2-resident)
            f32x4 bb[2][4];
            #pragma unroll
            for (int jh = 0; jh < 2; ++jh)
                #pragma unroll
                for (int it = 0; it < 4; ++it)
                    bb[jh][it] = *(const f32x4*)(bh + (it*16 + l16)*64 + (ks*2+jh)*16 + quad*4);

            // S^T block: C-frag (jh,it): row j = ks*32+jh*16+quad*4+r, col i = it*16+l16
            f32x4 st[2][4];
            #pragma unroll
            for (int jh = 0; jh < 2; ++jh)
                #pragma unroll
                for (int it = 0; it < 4; ++it)
                    st[jh][it] = __builtin_amdgcn_mfma_f32_16x16x32_bf16(ak[ks*2+jh], bq[it], zero, 0, 0, 0);

            // P = exp2(S^T*SCLG2E + bias)  (no max-subtract: logits bounded)
            // pack 4 consecutive k-slots -> one ds_write_b64 into B-frag order
            #pragma unroll
            for (int it = 0; it < 4; ++it)
                #pragma unroll
                for (int jh = 0; jh < 2; ++jh) {
                    float e0 = __builtin_amdgcn_exp2f(st[jh][it][0]*SCLG2E + bb[jh][it][0]);
                    float e1 = __builtin_amdgcn_exp2f(st[jh][it][1]*SCLG2E + bb[jh][it][1]);
                    float e2 = __builtin_amdgcn_exp2f(st[jh][it][2]*SCLG2E + bb[jh][it][2]);
                    float e3 = __builtin_amdgcn_exp2f(st[jh][it][3]*SCLG2E + bb[jh][it][3]);
                    s[it] += (e0 + e1) + (e2 + e3);
                    bf16x4 pk4;
                    pk4[0] = (bf16_t)e0; pk4[1] = (bf16_t)e1;
                    pk4[2] = (bf16_t)e2; pk4[3] = (bf16_t)e3;
                    // k_local = jh*16+quad*4+r -> frag elem (2jh+qh)*128 + l16*8 + ql*4 + r
                    *(bf16x4*)(pb + it*512 + (2*jh + qh)*128 + l16*8 + ql*4) = pk4;
                }

            // PV: O^T += V^T[.,ks-block] * P^T[ks-block,.]
            #pragma unroll
            for (int it = 0; it < 4; ++it) {
                bf16x8 bp = ((const bf16x8*)(pb + it*512))[lane];
                accO[0][it] = __builtin_amdgcn_mfma_f32_16x16x32_bf16(av[0][ks], bp, accO[0][it], 0, 0, 0);
                accO[1][it] = __builtin_amdgcn_mfma_f32_16x16x32_bf16(av[1][ks], bp, accO[1][it], 0, 0, 0);
            }
        }

        // softmax denominators (quad reduce) + rescaled O -> obuf (packed b64)
        #pragma unroll
        for (int it = 0; it < 4; ++it) {
            float sv = s[it];
            sv += __shfl_xor(sv, 16);
            sv += __shfl_xor(sv, 32);
            float inv = __builtin_amdgcn_rcpf(sv);
            #pragma unroll
            for (int dt = 0; dt < 2; ++dt) {
                bf16x4 o4;
                #pragma unroll
                for (int r = 0; r < 4; ++r) o4[r] = (bf16_t)(accO[dt][it][r] * inv);
                // O[token i][dim d]: i = it*16+l16, d = h*32 + dt*16 + quad*4 + r
                *(bf16x4*)(obuf + (size_t)(b*64 + it*16 + l16)*DIM + h*32 + dt*16 + quad*4) = o4;
            }
        }
    }
}

// ---------------------------------------------------------------------------
extern "C" void kernel_launch(void* const* d_in, const int* in_sizes, int n_in,
                              void* d_out, int out_size, void* d_ws, size_t ws_size,
                              hipStream_t stream) {
    const float* x      = (const float*)d_in[0];
    const float* theta  = (const float*)d_in[1];
    const float* qkv_w  = (const float*)d_in[2];
    const float* qkv_b  = (const float*)d_in[3];
    const float* proj_w = (const float*)d_in[4];
    const float* proj_b = (const float*)d_in[5];
    const float* a_p    = (const float*)d_in[6];
    const float* b_p    = (const float*)d_in[7];
    const float* a_r    = (const float*)d_in[8];
    const float* b_r    = (const float*)d_in[9];
    float* out = (float*)d_out;

    // workspace layout (all 256B aligned)
    char* ws = (char*)d_ws;
    bf16_t* qkvbuf = (bf16_t*)ws;                                  // 65536*1536 bf16 = 192MB
    bf16_t* xb     = (bf16_t*)(ws + 201326592);                    // 65536*512  bf16 = 64MB
    bf16_t* wqkv   = (bf16_t*)(ws + 201326592 + 67108864);         // 1536*512 bf16
    bf16_t* wproj  = (bf16_t*)(ws + 201326592 + 67108864 + 1572864);
    float*  biasbf = (float*) (ws + 201326592 + 67108864 + 1572864 + 524288);
    bf16_t* obuf   = xb;   // xb is dead after the qkv GEMM; reuse (stream-ordered)

    // 1) converts
    cvt_f32_bf16<<<(MTOT*DIM/8)/256, 256, 0, stream>>>(x, xb, MTOT*DIM/8);
    cvt_f32_bf16<<<(QKVN*DIM/8)/256, 256, 0, stream>>>(qkv_w, wqkv, QKVN*DIM/8);
    cvt_f32_bf16<<<(DIM*DIM/8)/256, 256, 0, stream>>>(proj_w, wproj, DIM*DIM/8);

    // 2) bias table (layout [h][i][j], pre-scaled by log2e — consumed by attn)
    bias_kernel<<<256, 256, 0, stream>>>(a_p, b_p, a_r, b_r, theta, biasbf);

    // 3) qkv GEMM: M=65536 N=1536 K=512 (bf16 out)
    gemm_bt<1><<<(MTOT/128)*(QKVN/128), 256, 0, stream>>>(xb, wqkv, qkv_b, qkvbuf,
                                                          MTOT, QKVN, DIM, QKVN/128);
    // 4) attention (bf16 obuf out)
    attn_kernel<<<NWIN, 256, 0, stream>>>(qkvbuf, biasbf, obuf);

    // 5) proj GEMM: M=65536 N=512 K=512 (fp32 out + projb)
    gemm_bt<0><<<(MTOT/128)*(DIM/128), 256, 0, stream>>>(obuf, wproj, proj_b, out,
                                                         MTOT, DIM, DIM, DIM/128);
}